// Round 1
// baseline (2478.164 us; speedup 1.0000x reference)
//
#include <hip/hip_runtime.h>
#include <hip/hip_bf16.h>

#define DEVI __device__ __forceinline__

typedef __attribute__((ext_vector_type(8))) __bf16 bf16x8;
typedef __attribute__((ext_vector_type(4))) float f32x4;
typedef __attribute__((ext_vector_type(8))) unsigned short ushort8;

DEVI unsigned short f2bf(float f) {
    union { float f; unsigned u; } v; v.f = f;
    unsigned r = v.u + 0x7fffu + ((v.u >> 16) & 1u);
    return (unsigned short)(r >> 16);
}

DEVI void load_lds_16(const void* g, void* l) {
    __builtin_amdgcn_global_load_lds(
        (const __attribute__((address_space(1))) void*)g,
        (__attribute__((address_space(3))) void*)l, 16, 0, 0);
}

// ---------------- weight transpose+convert: in [K][N] f32 -> out [N][K] bf16 ----------------
__global__ __launch_bounds__(256) void k_transpose_w(const float* __restrict__ in,
                                                     unsigned short* __restrict__ out,
                                                     int K, int N) {
    __shared__ float tile[64][65];
    const int tk = blockIdx.x * 64, tn = blockIdx.y * 64;
    const int t = threadIdx.x;
    const int c4 = (t & 15) * 4, r0 = t >> 4;
#pragma unroll
    for (int p = 0; p < 4; ++p) {
        int r = r0 + p * 16;
        float4 v = *reinterpret_cast<const float4*>(&in[(size_t)(tk + r) * N + tn + c4]);
        tile[r][c4 + 0] = v.x; tile[r][c4 + 1] = v.y;
        tile[r][c4 + 2] = v.z; tile[r][c4 + 3] = v.w;
    }
    __syncthreads();
#pragma unroll
    for (int p = 0; p < 4; ++p) {
        int n = r0 + p * 16;
        ushort4 o;
        o.x = f2bf(tile[c4 + 0][n]); o.y = f2bf(tile[c4 + 1][n]);
        o.z = f2bf(tile[c4 + 2][n]); o.w = f2bf(tile[c4 + 3][n]);
        *reinterpret_cast<ushort4*>(&out[(size_t)(tn + n) * K + tk + c4]) = o;
    }
}

// ---------------- V transpose: qkv bf16 V-part [s][d] -> vt [bh][d][s] bf16 ----------------
__global__ __launch_bounds__(256) void k_transpose_v(const unsigned short* __restrict__ qkv,
                                                     unsigned short* __restrict__ vt) {
    __shared__ unsigned short tile[64][72];
    const int ts = blockIdx.x * 64;   // s tile
    const int td = blockIdx.y * 64;   // d tile
    const int bh = blockIdx.z;
    const int b = bh >> 4, h = bh & 15;
    const unsigned short* src = qkv + (size_t)b * 2048 * 6144 + 4096 + h * 128;
    const int t = threadIdx.x;
    const int c8 = (t & 7) * 8, r0 = t >> 3; // r0: 0..31
#pragma unroll
    for (int p = 0; p < 2; ++p) {
        int r = r0 + p * 32;
        const unsigned short* sp = &src[(size_t)(ts + r) * 6144 + td + c8];
        ushort4 a0 = *reinterpret_cast<const ushort4*>(sp);
        ushort4 a1 = *reinterpret_cast<const ushort4*>(sp + 4);
        tile[r][c8 + 0] = a0.x; tile[r][c8 + 1] = a0.y; tile[r][c8 + 2] = a0.z; tile[r][c8 + 3] = a0.w;
        tile[r][c8 + 4] = a1.x; tile[r][c8 + 5] = a1.y; tile[r][c8 + 6] = a1.z; tile[r][c8 + 7] = a1.w;
    }
    __syncthreads();
    unsigned short* dst = vt + ((size_t)bh * 128 + td) * 2048 + ts;
#pragma unroll
    for (int p = 0; p < 2; ++p) {
        int d = r0 + p * 32;
        ushort4 o0, o1;
        o0.x = tile[c8 + 0][d]; o0.y = tile[c8 + 1][d]; o0.z = tile[c8 + 2][d]; o0.w = tile[c8 + 3][d];
        o1.x = tile[c8 + 4][d]; o1.y = tile[c8 + 5][d]; o1.z = tile[c8 + 6][d]; o1.w = tile[c8 + 7][d];
        *reinterpret_cast<ushort4*>(&dst[(size_t)d * 2048 + c8]) = o0;
        *reinterpret_cast<ushort4*>(&dst[(size_t)d * 2048 + c8 + 4]) = o1;
    }
}

// ---------------- layernorm: fp32 [rows][2048] -> bf16, one block per row ----------------
__global__ __launch_bounds__(256) void k_layernorm(const float* __restrict__ x,
                                                   const float* __restrict__ g,
                                                   const float* __restrict__ bb,
                                                   unsigned short* __restrict__ out) {
    const int row = blockIdx.x;
    const int t = threadIdx.x;
    const float* xr = x + (size_t)row * 2048 + t * 8;
    float4 v0 = *reinterpret_cast<const float4*>(xr);
    float4 v1 = *reinterpret_cast<const float4*>(xr + 4);
    float s = (v0.x + v0.y) + (v0.z + v0.w) + (v1.x + v1.y) + (v1.z + v1.w);
    float ss = (v0.x * v0.x + v0.y * v0.y) + (v0.z * v0.z + v0.w * v0.w)
             + (v1.x * v1.x + v1.y * v1.y) + (v1.z * v1.z + v1.w * v1.w);
#pragma unroll
    for (int m = 1; m < 64; m <<= 1) { s += __shfl_xor(s, m); ss += __shfl_xor(ss, m); }
    __shared__ float red[8];
    if ((t & 63) == 0) { red[t >> 6] = s; red[4 + (t >> 6)] = ss; }
    __syncthreads();
    s = (red[0] + red[1]) + (red[2] + red[3]);
    ss = (red[4] + red[5]) + (red[6] + red[7]);
    const float mu = s * (1.f / 2048.f);
    const float rstd = rsqrtf(ss * (1.f / 2048.f) - mu * mu + 1e-5f);
    const float4 g0 = *reinterpret_cast<const float4*>(g + t * 8);
    const float4 g1 = *reinterpret_cast<const float4*>(g + t * 8 + 4);
    const float4 b0 = *reinterpret_cast<const float4*>(bb + t * 8);
    const float4 b1 = *reinterpret_cast<const float4*>(bb + t * 8 + 4);
    ushort8 o;
    o[0] = f2bf((v0.x - mu) * rstd * g0.x + b0.x);
    o[1] = f2bf((v0.y - mu) * rstd * g0.y + b0.y);
    o[2] = f2bf((v0.z - mu) * rstd * g0.z + b0.z);
    o[3] = f2bf((v0.w - mu) * rstd * g0.w + b0.w);
    o[4] = f2bf((v1.x - mu) * rstd * g1.x + b1.x);
    o[5] = f2bf((v1.y - mu) * rstd * g1.y + b1.y);
    o[6] = f2bf((v1.z - mu) * rstd * g1.z + b1.z);
    o[7] = f2bf((v1.w - mu) * rstd * g1.w + b1.w);
    *reinterpret_cast<ushort8*>(out + (size_t)row * 2048 + t * 8) = o;
}

// ---------------- GEMM: A[M][K]bf16 * Bt[N][K]bf16 + bias, epilogue variants ----------------
// EPI 0: out bf16, cols<scale_cols scaled by `scale` (qkv, Q pre-scaled)
// EPI 1: out f32 = acc + bias + res (residual add)
// EPI 2: out bf16 = gelu_tanh(acc + bias)
template <int EPI>
__global__ __launch_bounds__(256) void k_gemm_bt(const unsigned short* __restrict__ A,
                                                 const unsigned short* __restrict__ Bt,
                                                 const float* __restrict__ bias,
                                                 const float* __restrict__ res,
                                                 void* __restrict__ outv,
                                                 int M, int N, int K,
                                                 int scale_cols, float scale) {
    __shared__ alignas(16) unsigned short A_s[128 * 64];
    __shared__ alignas(16) unsigned short B_s[128 * 64];
    const int bn = blockIdx.x * 128, bm = blockIdx.y * 128;
    const int t = threadIdx.x, lane = t & 63, wid = t >> 6;
    const int wr = wid >> 1, wc = wid & 1;

    const unsigned short* agbase = A  + (size_t)(bm + wid * 32 + (lane >> 3)) * K + (lane & 7) * 8;
    const unsigned short* bgbase = Bt + (size_t)(bn + wid * 32 + (lane >> 3)) * K + (lane & 7) * 8;

    f32x4 acc[4][4] = {};
    for (int k0 = 0; k0 < K; k0 += 64) {
#pragma unroll
        for (int i = 0; i < 4; ++i) {
            load_lds_16(agbase + (size_t)i * 8 * K + k0, &A_s[(wid * 4 + i) * 512]);
            load_lds_16(bgbase + (size_t)i * 8 * K + k0, &B_s[(wid * 4 + i) * 512]);
        }
        __syncthreads();
#pragma unroll
        for (int kk = 0; kk < 64; kk += 32) {
            bf16x8 af[4], bf[4];
#pragma unroll
            for (int r = 0; r < 4; ++r)
                af[r] = *reinterpret_cast<const bf16x8*>(
                    &A_s[(wr * 64 + r * 16 + (lane & 15)) * 64 + kk + (lane >> 4) * 8]);
#pragma unroll
            for (int c = 0; c < 4; ++c)
                bf[c] = *reinterpret_cast<const bf16x8*>(
                    &B_s[(wc * 64 + c * 16 + (lane & 15)) * 64 + kk + (lane >> 4) * 8]);
#pragma unroll
            for (int r = 0; r < 4; ++r)
#pragma unroll
                for (int c = 0; c < 4; ++c)
                    acc[r][c] = __builtin_amdgcn_mfma_f32_16x16x32_bf16(af[r], bf[c], acc[r][c], 0, 0, 0);
        }
        __syncthreads();
    }

    const int row0 = bm + wr * 64 + ((lane >> 4) << 2);
    const int col0 = bn + wc * 64 + (lane & 15);
#pragma unroll
    for (int c = 0; c < 4; ++c) {
        const int col = col0 + c * 16;
        const float bv = bias[col];
        const float qs = (EPI == 0 && col < scale_cols) ? scale : 1.f;
#pragma unroll
        for (int r = 0; r < 4; ++r) {
            const int row = row0 + r * 16;
#pragma unroll
            for (int j = 0; j < 4; ++j) {
                float v = acc[r][c][j] + bv;
                const size_t idx = (size_t)(row + j) * N + col;
                if (EPI == 0) {
                    ((unsigned short*)outv)[idx] = f2bf(v * qs);
                } else if (EPI == 1) {
                    ((float*)outv)[idx] = v + res[idx];
                } else {
                    float u = v + 0.044715f * v * v * v;
                    u = fminf(fmaxf(u, -40.f), 40.f);
                    float e = __expf(1.5957691216057308f * u); // 2*sqrt(2/pi)
                    float th = (e - 1.f) / (e + 1.f);
                    ((unsigned short*)outv)[idx] = f2bf(0.5f * v * (1.f + th));
                }
            }
        }
    }
}

// ---------------- flash attention, causal, H=16 Dh=128, k-tile 64 ----------------
__global__ __launch_bounds__(256) void k_attn(const unsigned short* __restrict__ qkv,
                                              const unsigned short* __restrict__ vt,
                                              unsigned short* __restrict__ out) {
    __shared__ alignas(16) unsigned short P_lds[4][16][72];
    const int blk = blockIdx.x;
    const int qt = blk & 31;
    const int bh = blk >> 5;
    const int b = bh >> 4, h = bh & 15;
    const int t = threadIdx.x, lane = t & 63, wid = t >> 6;
    const int l15 = lane & 15, l4 = lane >> 4;
    const int qrow0 = qt * 64 + wid * 16;

    const unsigned short* qp = qkv + (size_t)(b * 2048 + qrow0 + l15) * 6144 + h * 128 + l4 * 8;
    bf16x8 aQ[4];
#pragma unroll
    for (int s = 0; s < 4; ++s) aQ[s] = *reinterpret_cast<const bf16x8*>(qp + s * 32);

    const unsigned short* kp = qkv + (size_t)b * 2048 * 6144 + 2048 + h * 128 + l4 * 8;
    const unsigned short* vp = vt + ((size_t)bh * 128 + l15) * 2048 + l4 * 8;

    f32x4 oacc[8] = {};
    float m_run[4], l_run[4];
#pragma unroll
    for (int j = 0; j < 4; ++j) { m_run[j] = -1e30f; l_run[j] = 0.f; }

    const int kend = qt * 64 + 64;
    for (int k0 = 0; k0 < kend; k0 += 64) {
        f32x4 sc[4] = {};
#pragma unroll
        for (int ct = 0; ct < 4; ++ct) {
            const unsigned short* kr = kp + (size_t)(k0 + ct * 16 + l15) * 6144;
#pragma unroll
            for (int s = 0; s < 4; ++s) {
                bf16x8 bK = *reinterpret_cast<const bf16x8*>(kr + s * 32);
                sc[ct] = __builtin_amdgcn_mfma_f32_16x16x32_bf16(aQ[s], bK, sc[ct], 0, 0, 0);
            }
        }
        if (k0 + 63 > qrow0) { // tile may cross the diagonal for this wave
#pragma unroll
            for (int ct = 0; ct < 4; ++ct) {
                int colc = k0 + ct * 16 + l15;
#pragma unroll
                for (int j = 0; j < 4; ++j)
                    if (colc > qrow0 + l4 * 4 + j) sc[ct][j] = -1e30f;
            }
        }
        float alpha[4], tsum[4];
#pragma unroll
        for (int j = 0; j < 4; ++j) {
            float mx = fmaxf(fmaxf(sc[0][j], sc[1][j]), fmaxf(sc[2][j], sc[3][j]));
#pragma unroll
            for (int msk = 1; msk < 16; msk <<= 1) mx = fmaxf(mx, __shfl_xor(mx, msk));
            float mn = fmaxf(m_run[j], mx);
            alpha[j] = __expf(m_run[j] - mn);
            m_run[j] = mn;
            tsum[j] = 0.f;
        }
#pragma unroll
        for (int ct = 0; ct < 4; ++ct)
#pragma unroll
            for (int j = 0; j < 4; ++j) {
                float p = __expf(sc[ct][j] - m_run[j]);
                sc[ct][j] = p;
                tsum[j] += p;
            }
#pragma unroll
        for (int j = 0; j < 4; ++j) {
            float sm = tsum[j];
#pragma unroll
            for (int msk = 1; msk < 16; msk <<= 1) sm += __shfl_xor(sm, msk);
            l_run[j] = l_run[j] * alpha[j] + sm;
        }
#pragma unroll
        for (int dt = 0; dt < 8; ++dt)
#pragma unroll
            for (int j = 0; j < 4; ++j) oacc[dt][j] *= alpha[j];
        // P (C-layout) -> per-wave LDS -> A-fragments
#pragma unroll
        for (int ct = 0; ct < 4; ++ct)
#pragma unroll
            for (int j = 0; j < 4; ++j)
                P_lds[wid][l4 * 4 + j][ct * 16 + l15] = f2bf(sc[ct][j]);
        asm volatile("s_waitcnt lgkmcnt(0)" ::: "memory");
#pragma unroll
        for (int kk = 0; kk < 2; ++kk) {
            bf16x8 aP = *reinterpret_cast<const bf16x8*>(&P_lds[wid][l15][kk * 32 + l4 * 8]);
            const unsigned short* vr = vp + k0 + kk * 32;
#pragma unroll
            for (int dt = 0; dt < 8; ++dt) {
                bf16x8 bV = *reinterpret_cast<const bf16x8*>(vr + (size_t)dt * 16 * 2048);
                oacc[dt] = __builtin_amdgcn_mfma_f32_16x16x32_bf16(aP, bV, oacc[dt], 0, 0, 0);
            }
        }
        asm volatile("s_waitcnt lgkmcnt(0)" ::: "memory");
    }
    float inv_l[4];
#pragma unroll
    for (int j = 0; j < 4; ++j) inv_l[j] = 1.f / l_run[j];
    unsigned short* op = out + (size_t)(b * 2048 + qrow0 + l4 * 4) * 2048 + h * 128 + l15;
#pragma unroll
    for (int dt = 0; dt < 8; ++dt)
#pragma unroll
        for (int j = 0; j < 4; ++j)
            op[(size_t)j * 2048 + dt * 16] = f2bf(oacc[dt][j] * inv_l[j]);
}

// ---------------- launch ----------------
extern "C" void kernel_launch(void* const* d_in, const int* in_sizes, int n_in,
                              void* d_out, int out_size, void* d_ws, size_t ws_size,
                              hipStream_t stream) {
    const float* hidden = (const float*)d_in[0];
    const float* ln1_g = (const float*)d_in[1];
    const float* ln1_b = (const float*)d_in[2];
    const float* w_attn = (const float*)d_in[3];
    const float* b_attn = (const float*)d_in[4];
    const float* w_o = (const float*)d_in[5];
    const float* b_o = (const float*)d_in[6];
    const float* ln2_g = (const float*)d_in[7];
    const float* ln2_b = (const float*)d_in[8];
    const float* w_fc = (const float*)d_in[9];
    const float* b_fc = (const float*)d_in[10];
    const float* w_fcp = (const float*)d_in[11];
    const float* b_fcp = (const float*)d_in[12];
    float* outp = (float*)d_out;

    if (ws_size < 268435456u) return; // need 256 MiB scratch

    char* ws = (char*)d_ws;
    unsigned short* wT_attn = (unsigned short*)(ws + 0);          // [6144][2048]
    unsigned short* wT_o    = (unsigned short*)(ws + 25165824);   // [2048][2048]
    unsigned short* wT_fc   = (unsigned short*)(ws + 33554432);   // [8192][2048]
    unsigned short* wT_proj = (unsigned short*)(ws + 67108864);   // [2048][8192]
    unsigned short* buf_x   = (unsigned short*)(ws + 100663296);  // [8192][2048] (x1 / attn / x2)
    unsigned short* qkv_b   = (unsigned short*)(ws + 134217728);  // [8192][6144]
    unsigned short* vtb     = (unsigned short*)(ws + 234881024);  // [64*128][2048]
    unsigned short* act_b   = qkv_b;                              // [8192][8192] overlays qkv+vt

    // 1. weight convert+transpose to bf16 [N][K]
    k_transpose_w<<<dim3(32, 96), 256, 0, stream>>>(w_attn, wT_attn, 2048, 6144);
    k_transpose_w<<<dim3(32, 32), 256, 0, stream>>>(w_o, wT_o, 2048, 2048);
    k_transpose_w<<<dim3(32, 128), 256, 0, stream>>>(w_fc, wT_fc, 2048, 8192);
    k_transpose_w<<<dim3(128, 32), 256, 0, stream>>>(w_fcp, wT_proj, 8192, 2048);
    // 2. LN1: hidden -> bf16 x
    k_layernorm<<<8192, 256, 0, stream>>>(hidden, ln1_g, ln1_b, buf_x);
    // 3. qkv = x @ w_attn + b_attn (Q cols pre-scaled by Dh^-0.5)
    k_gemm_bt<0><<<dim3(48, 64), 256, 0, stream>>>(buf_x, wT_attn, b_attn, (const float*)nullptr,
                                                   (void*)qkv_b, 8192, 6144, 2048,
                                                   2048, 0.08838834764831845f);
    // 4. V -> Vt [bh][d][s]
    k_transpose_v<<<dim3(32, 2, 64), 256, 0, stream>>>(qkv_b, vtb);
    // 5. causal flash attention -> buf_x (bf16)
    k_attn<<<2048, 256, 0, stream>>>(qkv_b, vtb, buf_x);
    // 6. hidden2 = attn @ w_o + b_o + hidden -> d_out (f32)
    k_gemm_bt<1><<<dim3(16, 64), 256, 0, stream>>>(buf_x, wT_o, b_o, hidden,
                                                   d_out, 8192, 2048, 2048, 0, 1.f);
    // 7. LN2: d_out -> bf16 x2
    k_layernorm<<<8192, 256, 0, stream>>>(outp, ln2_g, ln2_b, buf_x);
    // 8. act = gelu(x2 @ w_fc + b_fc) -> bf16
    k_gemm_bt<2><<<dim3(64, 64), 256, 0, stream>>>(buf_x, wT_fc, b_fc, (const float*)nullptr,
                                                   (void*)act_b, 8192, 8192, 2048, 0, 1.f);
    // 9. out = act @ w_fc_proj + b_fc_proj + hidden2 (in-place on d_out)
    k_gemm_bt<1><<<dim3(16, 64), 256, 0, stream>>>(act_b, wT_proj, b_fcp, outp,
                                                   d_out, 8192, 2048, 8192, 0, 1.f);
}

// Round 2
// 1559.701 us; speedup vs baseline: 1.5889x; 1.5889x over previous
//
#include <hip/hip_runtime.h>
#include <hip/hip_bf16.h>

#define DEVI __device__ __forceinline__

typedef __attribute__((ext_vector_type(8))) __bf16 bf16x8;
typedef __attribute__((ext_vector_type(4))) float f32x4;
typedef __attribute__((ext_vector_type(8))) unsigned short ushort8;

DEVI unsigned short f2bf(float f) {
    union { float f; unsigned u; } v; v.f = f;
    unsigned r = v.u + 0x7fffu + ((v.u >> 16) & 1u);
    return (unsigned short)(r >> 16);
}

DEVI void load_lds_16(const void* g, void* l) {
    __builtin_amdgcn_global_load_lds(
        (const __attribute__((address_space(1))) void*)g,
        (__attribute__((address_space(3))) void*)l, 16, 0, 0);
}

// ---------------- weight transpose+convert: in [K][N] f32 -> out [N][K] bf16 ----------------
__global__ __launch_bounds__(256) void k_transpose_w(const float* __restrict__ in,
                                                     unsigned short* __restrict__ out,
                                                     int K, int N) {
    __shared__ float tile[64][65];
    const int tk = blockIdx.x * 64, tn = blockIdx.y * 64;
    const int t = threadIdx.x;
    const int c4 = (t & 15) * 4, r0 = t >> 4;
#pragma unroll
    for (int p = 0; p < 4; ++p) {
        int r = r0 + p * 16;
        float4 v = *reinterpret_cast<const float4*>(&in[(size_t)(tk + r) * N + tn + c4]);
        tile[r][c4 + 0] = v.x; tile[r][c4 + 1] = v.y;
        tile[r][c4 + 2] = v.z; tile[r][c4 + 3] = v.w;
    }
    __syncthreads();
#pragma unroll
    for (int p = 0; p < 4; ++p) {
        int n = r0 + p * 16;
        ushort4 o;
        o.x = f2bf(tile[c4 + 0][n]); o.y = f2bf(tile[c4 + 1][n]);
        o.z = f2bf(tile[c4 + 2][n]); o.w = f2bf(tile[c4 + 3][n]);
        *reinterpret_cast<ushort4*>(&out[(size_t)(tn + n) * K + tk + c4]) = o;
    }
}

// ---------------- V transpose: qkv bf16 V-part [s][d] -> vt [bh][d][s] bf16 ----------------
__global__ __launch_bounds__(256) void k_transpose_v(const unsigned short* __restrict__ qkv,
                                                     unsigned short* __restrict__ vt) {
    __shared__ unsigned short tile[64][72];
    const int ts = blockIdx.x * 64;   // s tile
    const int td = blockIdx.y * 64;   // d tile
    const int bh = blockIdx.z;
    const int b = bh >> 4, h = bh & 15;
    const unsigned short* src = qkv + (size_t)b * 2048 * 6144 + 4096 + h * 128;
    const int t = threadIdx.x;
    const int c8 = (t & 7) * 8, r0 = t >> 3; // r0: 0..31
#pragma unroll
    for (int p = 0; p < 2; ++p) {
        int r = r0 + p * 32;
        const unsigned short* sp = &src[(size_t)(ts + r) * 6144 + td + c8];
        ushort4 a0 = *reinterpret_cast<const ushort4*>(sp);
        ushort4 a1 = *reinterpret_cast<const ushort4*>(sp + 4);
        tile[r][c8 + 0] = a0.x; tile[r][c8 + 1] = a0.y; tile[r][c8 + 2] = a0.z; tile[r][c8 + 3] = a0.w;
        tile[r][c8 + 4] = a1.x; tile[r][c8 + 5] = a1.y; tile[r][c8 + 6] = a1.z; tile[r][c8 + 7] = a1.w;
    }
    __syncthreads();
    unsigned short* dst = vt + ((size_t)bh * 128 + td) * 2048 + ts;
#pragma unroll
    for (int p = 0; p < 2; ++p) {
        int d = r0 + p * 32;
        ushort4 o0, o1;
        o0.x = tile[c8 + 0][d]; o0.y = tile[c8 + 1][d]; o0.z = tile[c8 + 2][d]; o0.w = tile[c8 + 3][d];
        o1.x = tile[c8 + 4][d]; o1.y = tile[c8 + 5][d]; o1.z = tile[c8 + 6][d]; o1.w = tile[c8 + 7][d];
        *reinterpret_cast<ushort4*>(&dst[(size_t)d * 2048 + c8]) = o0;
        *reinterpret_cast<ushort4*>(&dst[(size_t)d * 2048 + c8 + 4]) = o1;
    }
}

// ---------------- layernorm: fp32 [rows][2048] -> bf16, one block per row ----------------
__global__ __launch_bounds__(256) void k_layernorm(const float* __restrict__ x,
                                                   const float* __restrict__ g,
                                                   const float* __restrict__ bb,
                                                   unsigned short* __restrict__ out) {
    const int row = blockIdx.x;
    const int t = threadIdx.x;
    const float* xr = x + (size_t)row * 2048 + t * 8;
    float4 v0 = *reinterpret_cast<const float4*>(xr);
    float4 v1 = *reinterpret_cast<const float4*>(xr + 4);
    float s = (v0.x + v0.y) + (v0.z + v0.w) + (v1.x + v1.y) + (v1.z + v1.w);
    float ss = (v0.x * v0.x + v0.y * v0.y) + (v0.z * v0.z + v0.w * v0.w)
             + (v1.x * v1.x + v1.y * v1.y) + (v1.z * v1.z + v1.w * v1.w);
#pragma unroll
    for (int m = 1; m < 64; m <<= 1) { s += __shfl_xor(s, m); ss += __shfl_xor(ss, m); }
    __shared__ float red[8];
    if ((t & 63) == 0) { red[t >> 6] = s; red[4 + (t >> 6)] = ss; }
    __syncthreads();
    s = (red[0] + red[1]) + (red[2] + red[3]);
    ss = (red[4] + red[5]) + (red[6] + red[7]);
    const float mu = s * (1.f / 2048.f);
    const float rstd = rsqrtf(ss * (1.f / 2048.f) - mu * mu + 1e-5f);
    const float4 g0 = *reinterpret_cast<const float4*>(g + t * 8);
    const float4 g1 = *reinterpret_cast<const float4*>(g + t * 8 + 4);
    const float4 b0 = *reinterpret_cast<const float4*>(bb + t * 8);
    const float4 b1 = *reinterpret_cast<const float4*>(bb + t * 8 + 4);
    ushort8 o;
    o[0] = f2bf((v0.x - mu) * rstd * g0.x + b0.x);
    o[1] = f2bf((v0.y - mu) * rstd * g0.y + b0.y);
    o[2] = f2bf((v0.z - mu) * rstd * g0.z + b0.z);
    o[3] = f2bf((v0.w - mu) * rstd * g0.w + b0.w);
    o[4] = f2bf((v1.x - mu) * rstd * g1.x + b1.x);
    o[5] = f2bf((v1.y - mu) * rstd * g1.y + b1.y);
    o[6] = f2bf((v1.z - mu) * rstd * g1.z + b1.z);
    o[7] = f2bf((v1.w - mu) * rstd * g1.w + b1.w);
    *reinterpret_cast<ushort8*>(out + (size_t)row * 2048 + t * 8) = o;
}

// ---------------- GEMM: A[M][K]bf16 * Bt[N][K]bf16 + bias, epilogue variants ----------------
template <int EPI>
__global__ __launch_bounds__(256) void k_gemm_bt(const unsigned short* __restrict__ A,
                                                 const unsigned short* __restrict__ Bt,
                                                 const float* __restrict__ bias,
                                                 const float* __restrict__ res,
                                                 void* __restrict__ outv,
                                                 int M, int N, int K,
                                                 int scale_cols, float scale) {
    __shared__ alignas(16) unsigned short A_s[128 * 64];
    __shared__ alignas(16) unsigned short B_s[128 * 64];
    const int bn = blockIdx.x * 128, bm = blockIdx.y * 128;
    const int t = threadIdx.x, lane = t & 63, wid = t >> 6;
    const int wr = wid >> 1, wc = wid & 1;

    const unsigned short* agbase = A  + (size_t)(bm + wid * 32 + (lane >> 3)) * K + (lane & 7) * 8;
    const unsigned short* bgbase = Bt + (size_t)(bn + wid * 32 + (lane >> 3)) * K + (lane & 7) * 8;

    f32x4 acc[4][4] = {};
    for (int k0 = 0; k0 < K; k0 += 64) {
#pragma unroll
        for (int i = 0; i < 4; ++i) {
            load_lds_16(agbase + (size_t)i * 8 * K + k0, &A_s[(wid * 4 + i) * 512]);
            load_lds_16(bgbase + (size_t)i * 8 * K + k0, &B_s[(wid * 4 + i) * 512]);
        }
        __syncthreads();
#pragma unroll
        for (int kk = 0; kk < 64; kk += 32) {
            bf16x8 af[4], bf[4];
#pragma unroll
            for (int r = 0; r < 4; ++r)
                af[r] = *reinterpret_cast<const bf16x8*>(
                    &A_s[(wr * 64 + r * 16 + (lane & 15)) * 64 + kk + (lane >> 4) * 8]);
#pragma unroll
            for (int c = 0; c < 4; ++c)
                bf[c] = *reinterpret_cast<const bf16x8*>(
                    &B_s[(wc * 64 + c * 16 + (lane & 15)) * 64 + kk + (lane >> 4) * 8]);
#pragma unroll
            for (int r = 0; r < 4; ++r)
#pragma unroll
                for (int c = 0; c < 4; ++c)
                    acc[r][c] = __builtin_amdgcn_mfma_f32_16x16x32_bf16(af[r], bf[c], acc[r][c], 0, 0, 0);
        }
        __syncthreads();
    }

    const int row0 = bm + wr * 64 + ((lane >> 4) << 2);
    const int col0 = bn + wc * 64 + (lane & 15);
#pragma unroll
    for (int c = 0; c < 4; ++c) {
        const int col = col0 + c * 16;
        const float bv = bias[col];
        const float qs = (EPI == 0 && col < scale_cols) ? scale : 1.f;
#pragma unroll
        for (int r = 0; r < 4; ++r) {
            const int row = row0 + r * 16;
#pragma unroll
            for (int j = 0; j < 4; ++j) {
                float v = acc[r][c][j] + bv;
                const size_t idx = (size_t)(row + j) * N + col;
                if (EPI == 0) {
                    ((unsigned short*)outv)[idx] = f2bf(v * qs);
                } else if (EPI == 1) {
                    ((float*)outv)[idx] = v + res[idx];
                } else {
                    float u = v + 0.044715f * v * v * v;
                    u = fminf(fmaxf(u, -40.f), 40.f);
                    float e = __expf(1.5957691216057308f * u); // 2*sqrt(2/pi)
                    float th = (e - 1.f) / (e + 1.f);
                    ((unsigned short*)outv)[idx] = f2bf(0.5f * v * (1.f + th));
                }
            }
        }
    }
}

// ---------------- flash attention v2: LDS-staged K/V, dbuf, pair-balanced, causal ----------------
// grid = 1024: xcd = blk&7, idx = blk>>3, bh = xcd*8 + idx/16, pair = idx%16.
// Block handles q-tiles {31-pair, pair} (64 rows each) => uniform 33 k-tile iters.
__global__ __launch_bounds__(256) void k_attn(const unsigned short* __restrict__ qkv,
                                              const unsigned short* __restrict__ vt,
                                              unsigned short* __restrict__ out) {
    __shared__ alignas(16) unsigned short Ks[2][64 * 128];   // [s][d], granule-swizzled
    __shared__ alignas(16) unsigned short Vs[2][128 * 64];   // [d][s], granule-swizzled
    __shared__ alignas(16) unsigned short P_lds[4][16][72];

    const int p = blockIdx.x;
    const int bh = (p & 7) * 8 + ((p >> 3) >> 4);
    const int pair = (p >> 3) & 15;
    const int b = bh >> 4, h = bh & 15;
    const int t = threadIdx.x, lane = t & 63, wid = t >> 6;
    const int l15 = lane & 15, l4 = lane >> 4;

    // staging geometry (per wave: 4 K-chunks + 4 V-chunks of 1KB)
    const int kq = wid * 4;                 // first chunk index of this wave
    const int k_r0 = kq * 4 + (lane >> 4);  // K row for chunk kq (+i*4)
    const int k_g0 = lane & 15;             // physical granule (16B) within K row
    const int v_d0 = kq * 8 + (lane >> 3);  // V row (d) for chunk kq (+i*8)
    const int v_g0 = lane & 7;              // physical granule within V row

#pragma unroll
    for (int qi = 0; qi < 2; ++qi) {
        const int qt = qi ? pair : (31 - pair);
        const int qrow0 = qt * 64 + wid * 16;
        const int nt = qt + 1;

        // Q fragments (A-operand): row l15, k = l4*8 + s*32
        const unsigned short* qp = qkv + (size_t)(b * 2048 + qrow0 + l15) * 6144 + h * 128 + l4 * 8;
        bf16x8 aQ[4];
#pragma unroll
        for (int s = 0; s < 4; ++s) aQ[s] = *reinterpret_cast<const bf16x8*>(qp + s * 32);

        f32x4 oacc[8] = {};
        float m_run[4], l_run[4];
#pragma unroll
        for (int j = 0; j < 4; ++j) { m_run[j] = -1e30f; l_run[j] = 0.f; }

        // prologue: stage tile 0 into buffer 0
        {
#pragma unroll
            for (int i = 0; i < 4; ++i) {
                const int r = k_r0 + i * 4;
                const unsigned short* src = qkv + (size_t)(b * 2048 + r) * 6144 + 2048
                                            + h * 128 + (size_t)(k_g0 ^ (r & 7)) * 8;
                load_lds_16(src, &Ks[0][(kq + i) * 512]);
            }
#pragma unroll
            for (int i = 0; i < 4; ++i) {
                const int d = v_d0 + i * 8;
                const unsigned short* src = vt + ((size_t)bh * 128 + d) * 2048
                                            + (size_t)(v_g0 ^ (d & 7)) * 8;
                load_lds_16(src, &Vs[0][(kq + i) * 512]);
            }
        }

        for (int ti = 0; ti < nt; ++ti) {
            const int cur = ti & 1;
            const int k0 = ti * 64;
            if (ti + 1 < nt) {
                const int kn = k0 + 64;
#pragma unroll
                for (int i = 0; i < 4; ++i) {
                    const int r = k_r0 + i * 4;
                    const unsigned short* src = qkv + (size_t)(b * 2048 + kn + r) * 6144 + 2048
                                                + h * 128 + (size_t)(k_g0 ^ (r & 7)) * 8;
                    load_lds_16(src, &Ks[cur ^ 1][(kq + i) * 512]);
                }
#pragma unroll
                for (int i = 0; i < 4; ++i) {
                    const int d = v_d0 + i * 8;
                    const unsigned short* src = vt + ((size_t)bh * 128 + d) * 2048 + kn
                                                + (size_t)(v_g0 ^ (d & 7)) * 8;
                    load_lds_16(src, &Vs[cur ^ 1][(kq + i) * 512]);
                }
                asm volatile("s_waitcnt vmcnt(8)\n\ts_barrier" ::: "memory");
            } else {
                asm volatile("s_waitcnt vmcnt(0)\n\ts_barrier" ::: "memory");
            }

            // ---- QK^T from LDS ----
            f32x4 sc[4] = {};
#pragma unroll
            for (int s = 0; s < 4; ++s)
#pragma unroll
                for (int ct = 0; ct < 4; ++ct) {
                    bf16x8 bK = *reinterpret_cast<const bf16x8*>(
                        &Ks[cur][(ct * 16 + l15) * 128 + (((s * 4 + l4) ^ (l15 & 7)) << 3)]);
                    sc[ct] = __builtin_amdgcn_mfma_f32_16x16x32_bf16(aQ[s], bK, sc[ct], 0, 0, 0);
                }

            if (k0 + 63 > qrow0) { // causal mask for diagonal-crossing tiles
#pragma unroll
                for (int ct = 0; ct < 4; ++ct) {
                    int colc = k0 + ct * 16 + l15;
#pragma unroll
                    for (int j = 0; j < 4; ++j)
                        if (colc > qrow0 + l4 * 4 + j) sc[ct][j] = -1e30f;
                }
            }
            // ---- online softmax ----
            float alpha[4], tsum[4];
#pragma unroll
            for (int j = 0; j < 4; ++j) {
                float mx = fmaxf(fmaxf(sc[0][j], sc[1][j]), fmaxf(sc[2][j], sc[3][j]));
#pragma unroll
                for (int msk = 1; msk < 16; msk <<= 1) mx = fmaxf(mx, __shfl_xor(mx, msk));
                float mn = fmaxf(m_run[j], mx);
                alpha[j] = __expf(m_run[j] - mn);
                m_run[j] = mn;
                tsum[j] = 0.f;
            }
#pragma unroll
            for (int ct = 0; ct < 4; ++ct)
#pragma unroll
                for (int j = 0; j < 4; ++j) {
                    float pp = __expf(sc[ct][j] - m_run[j]);
                    sc[ct][j] = pp;
                    tsum[j] += pp;
                }
#pragma unroll
            for (int j = 0; j < 4; ++j) {
                float sm = tsum[j];
#pragma unroll
                for (int msk = 1; msk < 16; msk <<= 1) sm += __shfl_xor(sm, msk);
                l_run[j] = l_run[j] * alpha[j] + sm;
            }
#pragma unroll
            for (int dt = 0; dt < 8; ++dt)
#pragma unroll
                for (int j = 0; j < 4; ++j) oacc[dt][j] *= alpha[j];

            // ---- P (C-layout) -> per-wave LDS -> A-fragments ----
#pragma unroll
            for (int ct = 0; ct < 4; ++ct)
#pragma unroll
                for (int j = 0; j < 4; ++j)
                    P_lds[wid][l4 * 4 + j][ct * 16 + l15] = f2bf(sc[ct][j]);
            asm volatile("s_waitcnt lgkmcnt(0)" ::: "memory");
            // ---- PV from LDS ----
#pragma unroll
            for (int kk = 0; kk < 2; ++kk) {
                bf16x8 aP = *reinterpret_cast<const bf16x8*>(&P_lds[wid][l15][kk * 32 + l4 * 8]);
#pragma unroll
                for (int dt = 0; dt < 8; ++dt) {
                    bf16x8 bV = *reinterpret_cast<const bf16x8*>(
                        &Vs[cur][(dt * 16 + l15) * 64 + (((kk * 4 + l4) ^ (l15 & 7)) << 3)]);
                    oacc[dt] = __builtin_amdgcn_mfma_f32_16x16x32_bf16(aP, bV, oacc[dt], 0, 0, 0);
                }
            }
            asm volatile("s_waitcnt lgkmcnt(0)\n\ts_barrier" ::: "memory");
        }

        float inv_l[4];
#pragma unroll
        for (int j = 0; j < 4; ++j) inv_l[j] = 1.f / l_run[j];
        unsigned short* op = out + (size_t)(b * 2048 + qrow0 + l4 * 4) * 2048 + h * 128 + l15;
#pragma unroll
        for (int dt = 0; dt < 8; ++dt)
#pragma unroll
            for (int j = 0; j < 4; ++j)
                op[(size_t)j * 2048 + dt * 16] = f2bf(oacc[dt][j] * inv_l[j]);
    }
}

// ---------------- launch ----------------
extern "C" void kernel_launch(void* const* d_in, const int* in_sizes, int n_in,
                              void* d_out, int out_size, void* d_ws, size_t ws_size,
                              hipStream_t stream) {
    const float* hidden = (const float*)d_in[0];
    const float* ln1_g = (const float*)d_in[1];
    const float* ln1_b = (const float*)d_in[2];
    const float* w_attn = (const float*)d_in[3];
    const float* b_attn = (const float*)d_in[4];
    const float* w_o = (const float*)d_in[5];
    const float* b_o = (const float*)d_in[6];
    const float* ln2_g = (const float*)d_in[7];
    const float* ln2_b = (const float*)d_in[8];
    const float* w_fc = (const float*)d_in[9];
    const float* b_fc = (const float*)d_in[10];
    const float* w_fcp = (const float*)d_in[11];
    const float* b_fcp = (const float*)d_in[12];
    float* outp = (float*)d_out;

    if (ws_size < 268435456u) return; // need 256 MiB scratch

    char* ws = (char*)d_ws;
    unsigned short* wT_attn = (unsigned short*)(ws + 0);          // [6144][2048]
    unsigned short* wT_o    = (unsigned short*)(ws + 25165824);   // [2048][2048]
    unsigned short* wT_fc   = (unsigned short*)(ws + 33554432);   // [8192][2048]
    unsigned short* wT_proj = (unsigned short*)(ws + 67108864);   // [2048][8192]
    unsigned short* buf_x   = (unsigned short*)(ws + 100663296);  // [8192][2048] (x1 / attn / x2)
    unsigned short* qkv_b   = (unsigned short*)(ws + 134217728);  // [8192][6144]
    unsigned short* vtb     = (unsigned short*)(ws + 234881024);  // [64*128][2048]
    unsigned short* act_b   = qkv_b;                              // [8192][8192] overlays qkv+vt

    // 1. weight convert+transpose to bf16 [N][K]
    k_transpose_w<<<dim3(32, 96), 256, 0, stream>>>(w_attn, wT_attn, 2048, 6144);
    k_transpose_w<<<dim3(32, 32), 256, 0, stream>>>(w_o, wT_o, 2048, 2048);
    k_transpose_w<<<dim3(32, 128), 256, 0, stream>>>(w_fc, wT_fc, 2048, 8192);
    k_transpose_w<<<dim3(128, 32), 256, 0, stream>>>(w_fcp, wT_proj, 8192, 2048);
    // 2. LN1: hidden -> bf16 x
    k_layernorm<<<8192, 256, 0, stream>>>(hidden, ln1_g, ln1_b, buf_x);
    // 3. qkv = x @ w_attn + b_attn (Q cols pre-scaled by Dh^-0.5)
    k_gemm_bt<0><<<dim3(48, 64), 256, 0, stream>>>(buf_x, wT_attn, b_attn, (const float*)nullptr,
                                                   (void*)qkv_b, 8192, 6144, 2048,
                                                   2048, 0.08838834764831845f);
    // 4. V -> Vt [bh][d][s]
    k_transpose_v<<<dim3(32, 2, 64), 256, 0, stream>>>(qkv_b, vtb);
    // 5. causal flash attention -> buf_x (bf16)
    k_attn<<<1024, 256, 0, stream>>>(qkv_b, vtb, buf_x);
    // 6. hidden2 = attn @ w_o + b_o + hidden -> d_out (f32)
    k_gemm_bt<1><<<dim3(16, 64), 256, 0, stream>>>(buf_x, wT_o, b_o, hidden,
                                                   d_out, 8192, 2048, 2048, 0, 1.f);
    // 7. LN2: d_out -> bf16 x2
    k_layernorm<<<8192, 256, 0, stream>>>(outp, ln2_g, ln2_b, buf_x);
    // 8. act = gelu(x2 @ w_fc + b_fc) -> bf16
    k_gemm_bt<2><<<dim3(64, 64), 256, 0, stream>>>(buf_x, wT_fc, b_fc, (const float*)nullptr,
                                                   (void*)act_b, 8192, 8192, 2048, 0, 1.f);
    // 9. out = act @ w_fc_proj + b_fc_proj + hidden2 (in-place on d_out)
    k_gemm_bt<1><<<dim3(16, 64), 256, 0, stream>>>(act_b, wT_proj, b_fcp, outp,
                                                   d_out, 8192, 2048, 8192, 0, 1.f);
}

// Round 3
// 1559.048 us; speedup vs baseline: 1.5895x; 1.0004x over previous
//
#include <hip/hip_runtime.h>
#include <hip/hip_bf16.h>

#define DEVI __device__ __forceinline__

typedef __attribute__((ext_vector_type(8))) __bf16 bf16x8;
typedef __attribute__((ext_vector_type(4))) float f32x4;
typedef __attribute__((ext_vector_type(8))) unsigned short ushort8;

DEVI unsigned short f2bf(float f) {
    union { float f; unsigned u; } v; v.f = f;
    unsigned r = v.u + 0x7fffu + ((v.u >> 16) & 1u);
    return (unsigned short)(r >> 16);
}

DEVI void load_lds_16(const void* g, void* l) {
    __builtin_amdgcn_global_load_lds(
        (const __attribute__((address_space(1))) void*)g,
        (__attribute__((address_space(3))) void*)l, 16, 0, 0);
}

// ---------------- weight transpose+convert: in [K][N] f32 -> out [N][K] bf16 ----------------
__global__ __launch_bounds__(256) void k_transpose_w(const float* __restrict__ in,
                                                     unsigned short* __restrict__ out,
                                                     int K, int N) {
    __shared__ float tile[64][65];
    const int tk = blockIdx.x * 64, tn = blockIdx.y * 64;
    const int t = threadIdx.x;
    const int c4 = (t & 15) * 4, r0 = t >> 4;
#pragma unroll
    for (int p = 0; p < 4; ++p) {
        int r = r0 + p * 16;
        float4 v = *reinterpret_cast<const float4*>(&in[(size_t)(tk + r) * N + tn + c4]);
        tile[r][c4 + 0] = v.x; tile[r][c4 + 1] = v.y;
        tile[r][c4 + 2] = v.z; tile[r][c4 + 3] = v.w;
    }
    __syncthreads();
#pragma unroll
    for (int p = 0; p < 4; ++p) {
        int n = r0 + p * 16;
        ushort4 o;
        o.x = f2bf(tile[c4 + 0][n]); o.y = f2bf(tile[c4 + 1][n]);
        o.z = f2bf(tile[c4 + 2][n]); o.w = f2bf(tile[c4 + 3][n]);
        *reinterpret_cast<ushort4*>(&out[(size_t)(tn + n) * K + tk + c4]) = o;
    }
}

// ---------------- V transpose: qkv bf16 V-part [s][d] -> vt [bh][d][s] bf16 ----------------
__global__ __launch_bounds__(256) void k_transpose_v(const unsigned short* __restrict__ qkv,
                                                     unsigned short* __restrict__ vt) {
    __shared__ unsigned short tile[64][72];
    const int ts = blockIdx.x * 64;   // s tile
    const int td = blockIdx.y * 64;   // d tile
    const int bh = blockIdx.z;
    const int b = bh >> 4, h = bh & 15;
    const unsigned short* src = qkv + (size_t)b * 2048 * 6144 + 4096 + h * 128;
    const int t = threadIdx.x;
    const int c8 = (t & 7) * 8, r0 = t >> 3; // r0: 0..31
#pragma unroll
    for (int p = 0; p < 2; ++p) {
        int r = r0 + p * 32;
        const unsigned short* sp = &src[(size_t)(ts + r) * 6144 + td + c8];
        ushort4 a0 = *reinterpret_cast<const ushort4*>(sp);
        ushort4 a1 = *reinterpret_cast<const ushort4*>(sp + 4);
        tile[r][c8 + 0] = a0.x; tile[r][c8 + 1] = a0.y; tile[r][c8 + 2] = a0.z; tile[r][c8 + 3] = a0.w;
        tile[r][c8 + 4] = a1.x; tile[r][c8 + 5] = a1.y; tile[r][c8 + 6] = a1.z; tile[r][c8 + 7] = a1.w;
    }
    __syncthreads();
    unsigned short* dst = vt + ((size_t)bh * 128 + td) * 2048 + ts;
#pragma unroll
    for (int p = 0; p < 2; ++p) {
        int d = r0 + p * 32;
        ushort4 o0, o1;
        o0.x = tile[c8 + 0][d]; o0.y = tile[c8 + 1][d]; o0.z = tile[c8 + 2][d]; o0.w = tile[c8 + 3][d];
        o1.x = tile[c8 + 4][d]; o1.y = tile[c8 + 5][d]; o1.z = tile[c8 + 6][d]; o1.w = tile[c8 + 7][d];
        *reinterpret_cast<ushort4*>(&dst[(size_t)d * 2048 + c8]) = o0;
        *reinterpret_cast<ushort4*>(&dst[(size_t)d * 2048 + c8 + 4]) = o1;
    }
}

// ---------------- layernorm: fp32 [rows][2048] -> bf16, one block per row ----------------
__global__ __launch_bounds__(256) void k_layernorm(const float* __restrict__ x,
                                                   const float* __restrict__ g,
                                                   const float* __restrict__ bb,
                                                   unsigned short* __restrict__ out) {
    const int row = blockIdx.x;
    const int t = threadIdx.x;
    const float* xr = x + (size_t)row * 2048 + t * 8;
    float4 v0 = *reinterpret_cast<const float4*>(xr);
    float4 v1 = *reinterpret_cast<const float4*>(xr + 4);
    float s = (v0.x + v0.y) + (v0.z + v0.w) + (v1.x + v1.y) + (v1.z + v1.w);
    float ss = (v0.x * v0.x + v0.y * v0.y) + (v0.z * v0.z + v0.w * v0.w)
             + (v1.x * v1.x + v1.y * v1.y) + (v1.z * v1.z + v1.w * v1.w);
#pragma unroll
    for (int m = 1; m < 64; m <<= 1) { s += __shfl_xor(s, m); ss += __shfl_xor(ss, m); }
    __shared__ float red[8];
    if ((t & 63) == 0) { red[t >> 6] = s; red[4 + (t >> 6)] = ss; }
    __syncthreads();
    s = (red[0] + red[1]) + (red[2] + red[3]);
    ss = (red[4] + red[5]) + (red[6] + red[7]);
    const float mu = s * (1.f / 2048.f);
    const float rstd = rsqrtf(ss * (1.f / 2048.f) - mu * mu + 1e-5f);
    const float4 g0 = *reinterpret_cast<const float4*>(g + t * 8);
    const float4 g1 = *reinterpret_cast<const float4*>(g + t * 8 + 4);
    const float4 b0 = *reinterpret_cast<const float4*>(bb + t * 8);
    const float4 b1 = *reinterpret_cast<const float4*>(bb + t * 8 + 4);
    ushort8 o;
    o[0] = f2bf((v0.x - mu) * rstd * g0.x + b0.x);
    o[1] = f2bf((v0.y - mu) * rstd * g0.y + b0.y);
    o[2] = f2bf((v0.z - mu) * rstd * g0.z + b0.z);
    o[3] = f2bf((v0.w - mu) * rstd * g0.w + b0.w);
    o[4] = f2bf((v1.x - mu) * rstd * g1.x + b1.x);
    o[5] = f2bf((v1.y - mu) * rstd * g1.y + b1.y);
    o[6] = f2bf((v1.z - mu) * rstd * g1.z + b1.z);
    o[7] = f2bf((v1.w - mu) * rstd * g1.w + b1.w);
    *reinterpret_cast<ushort8*>(out + (size_t)row * 2048 + t * 8) = o;
}

// ---------------- GEMM: A[M][K]bf16 * Bt[N][K]bf16 + bias, epilogue variants ----------------
template <int EPI>
__global__ __launch_bounds__(256) void k_gemm_bt(const unsigned short* __restrict__ A,
                                                 const unsigned short* __restrict__ Bt,
                                                 const float* __restrict__ bias,
                                                 const float* __restrict__ res,
                                                 void* __restrict__ outv,
                                                 int M, int N, int K,
                                                 int scale_cols, float scale) {
    __shared__ alignas(16) unsigned short A_s[128 * 64];
    __shared__ alignas(16) unsigned short B_s[128 * 64];
    const int bn = blockIdx.x * 128, bm = blockIdx.y * 128;
    const int t = threadIdx.x, lane = t & 63, wid = t >> 6;
    const int wr = wid >> 1, wc = wid & 1;

    const unsigned short* agbase = A  + (size_t)(bm + wid * 32 + (lane >> 3)) * K + (lane & 7) * 8;
    const unsigned short* bgbase = Bt + (size_t)(bn + wid * 32 + (lane >> 3)) * K + (lane & 7) * 8;

    f32x4 acc[4][4] = {};
    for (int k0 = 0; k0 < K; k0 += 64) {
#pragma unroll
        for (int i = 0; i < 4; ++i) {
            load_lds_16(agbase + (size_t)i * 8 * K + k0, &A_s[(wid * 4 + i) * 512]);
            load_lds_16(bgbase + (size_t)i * 8 * K + k0, &B_s[(wid * 4 + i) * 512]);
        }
        __syncthreads();
#pragma unroll
        for (int kk = 0; kk < 64; kk += 32) {
            bf16x8 af[4], bf[4];
#pragma unroll
            for (int r = 0; r < 4; ++r)
                af[r] = *reinterpret_cast<const bf16x8*>(
                    &A_s[(wr * 64 + r * 16 + (lane & 15)) * 64 + kk + (lane >> 4) * 8]);
#pragma unroll
            for (int c = 0; c < 4; ++c)
                bf[c] = *reinterpret_cast<const bf16x8*>(
                    &B_s[(wc * 64 + c * 16 + (lane & 15)) * 64 + kk + (lane >> 4) * 8]);
#pragma unroll
            for (int r = 0; r < 4; ++r)
#pragma unroll
                for (int c = 0; c < 4; ++c)
                    acc[r][c] = __builtin_amdgcn_mfma_f32_16x16x32_bf16(af[r], bf[c], acc[r][c], 0, 0, 0);
        }
        __syncthreads();
    }

    const int row0 = bm + wr * 64 + ((lane >> 4) << 2);
    const int col0 = bn + wc * 64 + (lane & 15);
#pragma unroll
    for (int c = 0; c < 4; ++c) {
        const int col = col0 + c * 16;
        const float bv = bias[col];
        const float qs = (EPI == 0 && col < scale_cols) ? scale : 1.f;
#pragma unroll
        for (int r = 0; r < 4; ++r) {
            const int row = row0 + r * 16;
#pragma unroll
            for (int j = 0; j < 4; ++j) {
                float v = acc[r][c][j] + bv;
                const size_t idx = (size_t)(row + j) * N + col;
                if (EPI == 0) {
                    ((unsigned short*)outv)[idx] = f2bf(v * qs);
                } else if (EPI == 1) {
                    ((float*)outv)[idx] = v + res[idx];
                } else {
                    float u = v + 0.044715f * v * v * v;
                    u = fminf(fmaxf(u, -40.f), 40.f);
                    float e = __expf(1.5957691216057308f * u); // 2*sqrt(2/pi)
                    float th = (e - 1.f) / (e + 1.f);
                    ((unsigned short*)outv)[idx] = f2bf(0.5f * v * (1.f + th));
                }
            }
        }
    }
}

// ---------------- flash attention v2: LDS-staged K/V, dbuf, pair-balanced, causal ----------------
// grid = 1024: xcd = blk&7, idx = blk>>3, bh = xcd*8 + idx/16, pair = idx%16.
// Block handles q-tiles {31-pair, pair} (64 rows each) => uniform 33 k-tile iters.
__global__ __launch_bounds__(256) void k_attn(const unsigned short* __restrict__ qkv,
                                              const unsigned short* __restrict__ vt,
                                              unsigned short* __restrict__ out) {
    __shared__ alignas(16) unsigned short Ks[2][64 * 128];   // [s][d], granule-swizzled
    __shared__ alignas(16) unsigned short Vs[2][128 * 64];   // [d][s], granule-swizzled
    __shared__ alignas(16) unsigned short P_lds[4][16][72];

    const int p = blockIdx.x;
    const int bh = (p & 7) * 8 + ((p >> 3) >> 4);
    const int pair = (p >> 3) & 15;
    const int b = bh >> 4, h = bh & 15;
    const int t = threadIdx.x, lane = t & 63, wid = t >> 6;
    const int l15 = lane & 15, l4 = lane >> 4;

    // staging geometry (per wave: 4 K-chunks + 4 V-chunks of 1KB)
    const int kq = wid * 4;                 // first chunk index of this wave
    const int k_r0 = kq * 4 + (lane >> 4);  // K row for chunk kq (+i*4)
    const int k_g0 = lane & 15;             // physical granule (16B) within K row
    const int v_d0 = kq * 8 + (lane >> 3);  // V row (d) for chunk kq (+i*8)
    const int v_g0 = lane & 7;              // physical granule within V row

#pragma unroll
    for (int qi = 0; qi < 2; ++qi) {
        const int qt = qi ? pair : (31 - pair);
        const int qrow0 = qt * 64 + wid * 16;
        const int nt = qt + 1;

        // Q fragments (A-operand): row l15, k = l4*8 + s*32
        const unsigned short* qp = qkv + (size_t)(b * 2048 + qrow0 + l15) * 6144 + h * 128 + l4 * 8;
        bf16x8 aQ[4];
#pragma unroll
        for (int s = 0; s < 4; ++s) aQ[s] = *reinterpret_cast<const bf16x8*>(qp + s * 32);

        f32x4 oacc[8] = {};
        float m_run[4], l_run[4];
#pragma unroll
        for (int j = 0; j < 4; ++j) { m_run[j] = -1e30f; l_run[j] = 0.f; }

        // prologue: stage tile 0 into buffer 0
        {
#pragma unroll
            for (int i = 0; i < 4; ++i) {
                const int r = k_r0 + i * 4;
                const unsigned short* src = qkv + (size_t)(b * 2048 + r) * 6144 + 2048
                                            + h * 128 + (size_t)(k_g0 ^ (r & 7)) * 8;
                load_lds_16(src, &Ks[0][(kq + i) * 512]);
            }
#pragma unroll
            for (int i = 0; i < 4; ++i) {
                const int d = v_d0 + i * 8;
                const unsigned short* src = vt + ((size_t)bh * 128 + d) * 2048
                                            + (size_t)(v_g0 ^ (d & 7)) * 8;
                load_lds_16(src, &Vs[0][(kq + i) * 512]);
            }
        }

        for (int ti = 0; ti < nt; ++ti) {
            const int cur = ti & 1;
            const int k0 = ti * 64;
            if (ti + 1 < nt) {
                const int kn = k0 + 64;
#pragma unroll
                for (int i = 0; i < 4; ++i) {
                    const int r = k_r0 + i * 4;
                    const unsigned short* src = qkv + (size_t)(b * 2048 + kn + r) * 6144 + 2048
                                                + h * 128 + (size_t)(k_g0 ^ (r & 7)) * 8;
                    load_lds_16(src, &Ks[cur ^ 1][(kq + i) * 512]);
                }
#pragma unroll
                for (int i = 0; i < 4; ++i) {
                    const int d = v_d0 + i * 8;
                    const unsigned short* src = vt + ((size_t)bh * 128 + d) * 2048 + kn
                                                + (size_t)(v_g0 ^ (d & 7)) * 8;
                    load_lds_16(src, &Vs[cur ^ 1][(kq + i) * 512]);
                }
                asm volatile("s_waitcnt vmcnt(8)\n\ts_barrier" ::: "memory");
            } else {
                asm volatile("s_waitcnt vmcnt(0)\n\ts_barrier" ::: "memory");
            }

            // ---- QK^T from LDS ----
            f32x4 sc[4] = {};
#pragma unroll
            for (int s = 0; s < 4; ++s)
#pragma unroll
                for (int ct = 0; ct < 4; ++ct) {
                    bf16x8 bK = *reinterpret_cast<const bf16x8*>(
                        &Ks[cur][(ct * 16 + l15) * 128 + (((s * 4 + l4) ^ (l15 & 7)) << 3)]);
                    sc[ct] = __builtin_amdgcn_mfma_f32_16x16x32_bf16(aQ[s], bK, sc[ct], 0, 0, 0);
                }

            if (k0 + 63 > qrow0) { // causal mask for diagonal-crossing tiles
#pragma unroll
                for (int ct = 0; ct < 4; ++ct) {
                    int colc = k0 + ct * 16 + l15;
#pragma unroll
                    for (int j = 0; j < 4; ++j)
                        if (colc > qrow0 + l4 * 4 + j) sc[ct][j] = -1e30f;
                }
            }
            // ---- online softmax ----
            float alpha[4], tsum[4];
#pragma unroll
            for (int j = 0; j < 4; ++j) {
                float mx = fmaxf(fmaxf(sc[0][j], sc[1][j]), fmaxf(sc[2][j], sc[3][j]));
#pragma unroll
                for (int msk = 1; msk < 16; msk <<= 1) mx = fmaxf(mx, __shfl_xor(mx, msk));
                float mn = fmaxf(m_run[j], mx);
                alpha[j] = __expf(m_run[j] - mn);
                m_run[j] = mn;
                tsum[j] = 0.f;
            }
#pragma unroll
            for (int ct = 0; ct < 4; ++ct)
#pragma unroll
                for (int j = 0; j < 4; ++j) {
                    float pp = __expf(sc[ct][j] - m_run[j]);
                    sc[ct][j] = pp;
                    tsum[j] += pp;
                }
#pragma unroll
            for (int j = 0; j < 4; ++j) {
                float sm = tsum[j];
#pragma unroll
                for (int msk = 1; msk < 16; msk <<= 1) sm += __shfl_xor(sm, msk);
                l_run[j] = l_run[j] * alpha[j] + sm;
            }
#pragma unroll
            for (int dt = 0; dt < 8; ++dt)
#pragma unroll
                for (int j = 0; j < 4; ++j) oacc[dt][j] *= alpha[j];

            // ---- P (C-layout) -> per-wave LDS -> A-fragments ----
#pragma unroll
            for (int ct = 0; ct < 4; ++ct)
#pragma unroll
                for (int j = 0; j < 4; ++j)
                    P_lds[wid][l4 * 4 + j][ct * 16 + l15] = f2bf(sc[ct][j]);
            asm volatile("s_waitcnt lgkmcnt(0)" ::: "memory");
            // ---- PV from LDS ----
#pragma unroll
            for (int kk = 0; kk < 2; ++kk) {
                bf16x8 aP = *reinterpret_cast<const bf16x8*>(&P_lds[wid][l15][kk * 32 + l4 * 8]);
#pragma unroll
                for (int dt = 0; dt < 8; ++dt) {
                    bf16x8 bV = *reinterpret_cast<const bf16x8*>(
                        &Vs[cur][(dt * 16 + l15) * 64 + (((kk * 4 + l4) ^ (l15 & 7)) << 3)]);
                    oacc[dt] = __builtin_amdgcn_mfma_f32_16x16x32_bf16(aP, bV, oacc[dt], 0, 0, 0);
                }
            }
            asm volatile("s_waitcnt lgkmcnt(0)\n\ts_barrier" ::: "memory");
        }

        float inv_l[4];
#pragma unroll
        for (int j = 0; j < 4; ++j) inv_l[j] = 1.f / l_run[j];
        unsigned short* op = out + (size_t)(b * 2048 + qrow0 + l4 * 4) * 2048 + h * 128 + l15;
#pragma unroll
        for (int dt = 0; dt < 8; ++dt)
#pragma unroll
            for (int j = 0; j < 4; ++j)
                op[(size_t)j * 2048 + dt * 16] = f2bf(oacc[dt][j] * inv_l[j]);
    }
}

// ---------------- launch ----------------
extern "C" void kernel_launch(void* const* d_in, const int* in_sizes, int n_in,
                              void* d_out, int out_size, void* d_ws, size_t ws_size,
                              hipStream_t stream) {
    const float* hidden = (const float*)d_in[0];
    const float* ln1_g = (const float*)d_in[1];
    const float* ln1_b = (const float*)d_in[2];
    const float* w_attn = (const float*)d_in[3];
    const float* b_attn = (const float*)d_in[4];
    const float* w_o = (const float*)d_in[5];
    const float* b_o = (const float*)d_in[6];
    const float* ln2_g = (const float*)d_in[7];
    const float* ln2_b = (const float*)d_in[8];
    const float* w_fc = (const float*)d_in[9];
    const float* b_fc = (const float*)d_in[10];
    const float* w_fcp = (const float*)d_in[11];
    const float* b_fcp = (const float*)d_in[12];
    float* outp = (float*)d_out;

    if (ws_size < 268435456u) return; // need 256 MiB scratch

    char* ws = (char*)d_ws;
    unsigned short* wT_attn = (unsigned short*)(ws + 0);          // [6144][2048]
    unsigned short* wT_o    = (unsigned short*)(ws + 25165824);   // [2048][2048]
    unsigned short* wT_fc   = (unsigned short*)(ws + 33554432);   // [8192][2048]
    unsigned short* wT_proj = (unsigned short*)(ws + 67108864);   // [2048][8192]
    unsigned short* buf_x   = (unsigned short*)(ws + 100663296);  // [8192][2048] (x1 / attn / x2)
    unsigned short* qkv_b   = (unsigned short*)(ws + 134217728);  // [8192][6144]
    unsigned short* vtb     = (unsigned short*)(ws + 234881024);  // [64*128][2048]
    unsigned short* act_b   = qkv_b;                              // [8192][8192] overlays qkv+vt

    // 1. weight convert+transpose to bf16 [N][K]
    k_transpose_w<<<dim3(32, 96), 256, 0, stream>>>(w_attn, wT_attn, 2048, 6144);
    k_transpose_w<<<dim3(32, 32), 256, 0, stream>>>(w_o, wT_o, 2048, 2048);
    k_transpose_w<<<dim3(32, 128), 256, 0, stream>>>(w_fc, wT_fc, 2048, 8192);
    k_transpose_w<<<dim3(128, 32), 256, 0, stream>>>(w_fcp, wT_proj, 8192, 2048);
    // 2. LN1: hidden -> bf16 x
    k_layernorm<<<8192, 256, 0, stream>>>(hidden, ln1_g, ln1_b, buf_x);
    // 3. qkv = x @ w_attn + b_attn (Q cols pre-scaled by Dh^-0.5)
    k_gemm_bt<0><<<dim3(48, 64), 256, 0, stream>>>(buf_x, wT_attn, b_attn, (const float*)nullptr,
                                                   (void*)qkv_b, 8192, 6144, 2048,
                                                   2048, 0.08838834764831845f);
    // 4. V -> Vt [bh][d][s]
    k_transpose_v<<<dim3(32, 2, 64), 256, 0, stream>>>(qkv_b, vtb);
    // 5. causal flash attention -> buf_x (bf16)
    k_attn<<<1024, 256, 0, stream>>>(qkv_b, vtb, buf_x);
    // 6. hidden2 = attn @ w_o + b_o + hidden -> d_out (f32)
    k_gemm_bt<1><<<dim3(16, 64), 256, 0, stream>>>(buf_x, wT_o, b_o, hidden,
                                                   d_out, 8192, 2048, 2048, 0, 1.f);
    // 7. LN2: d_out -> bf16 x2
    k_layernorm<<<8192, 256, 0, stream>>>(outp, ln2_g, ln2_b, buf_x);
    // 8. act = gelu(x2 @ w_fc + b_fc) -> bf16
    k_gemm_bt<2><<<dim3(64, 64), 256, 0, stream>>>(buf_x, wT_fc, b_fc, (const float*)nullptr,
                                                   (void*)act_b, 8192, 8192, 2048, 0, 1.f);
    // 9. out = act @ w_fc_proj + b_fc_proj + hidden2 (in-place on d_out)
    k_gemm_bt<1><<<dim3(16, 64), 256, 0, stream>>>(act_b, wT_proj, b_fcp, outp,
                                                   d_out, 8192, 2048, 8192, 0, 1.f);
}

// Round 4
// 1557.633 us; speedup vs baseline: 1.5910x; 1.0009x over previous
//
#include <hip/hip_runtime.h>
#include <hip/hip_bf16.h>

#define DEVI __device__ __forceinline__

typedef __attribute__((ext_vector_type(8))) __bf16 bf16x8;
typedef __attribute__((ext_vector_type(4))) float f32x4;
typedef __attribute__((ext_vector_type(8))) unsigned short ushort8;

DEVI unsigned short f2bf(float f) {
    union { float f; unsigned u; } v; v.f = f;
    unsigned r = v.u + 0x7fffu + ((v.u >> 16) & 1u);
    return (unsigned short)(r >> 16);
}

DEVI void load_lds_16(const void* g, void* l) {
    __builtin_amdgcn_global_load_lds(
        (const __attribute__((address_space(1))) void*)g,
        (__attribute__((address_space(3))) void*)l, 16, 0, 0);
}

// ---------------- weight transpose+convert: in [K][N] f32 -> out [N][K] bf16 ----------------
__global__ __launch_bounds__(256) void k_transpose_w(const float* __restrict__ in,
                                                     unsigned short* __restrict__ out,
                                                     int K, int N) {
    __shared__ float tile[64][65];
    const int tk = blockIdx.x * 64, tn = blockIdx.y * 64;
    const int t = threadIdx.x;
    const int c4 = (t & 15) * 4, r0 = t >> 4;
#pragma unroll
    for (int p = 0; p < 4; ++p) {
        int r = r0 + p * 16;
        float4 v = *reinterpret_cast<const float4*>(&in[(size_t)(tk + r) * N + tn + c4]);
        tile[r][c4 + 0] = v.x; tile[r][c4 + 1] = v.y;
        tile[r][c4 + 2] = v.z; tile[r][c4 + 3] = v.w;
    }
    __syncthreads();
#pragma unroll
    for (int p = 0; p < 4; ++p) {
        int n = r0 + p * 16;
        ushort4 o;
        o.x = f2bf(tile[c4 + 0][n]); o.y = f2bf(tile[c4 + 1][n]);
        o.z = f2bf(tile[c4 + 2][n]); o.w = f2bf(tile[c4 + 3][n]);
        *reinterpret_cast<ushort4*>(&out[(size_t)(tn + n) * K + tk + c4]) = o;
    }
}

// ---------------- V transpose: qkv bf16 V-part [s][d] -> vt [bh][d][s] bf16 ----------------
__global__ __launch_bounds__(256) void k_transpose_v(const unsigned short* __restrict__ qkv,
                                                     unsigned short* __restrict__ vt) {
    __shared__ unsigned short tile[64][72];
    const int ts = blockIdx.x * 64;   // s tile
    const int td = blockIdx.y * 64;   // d tile
    const int bh = blockIdx.z;
    const int b = bh >> 4, h = bh & 15;
    const unsigned short* src = qkv + (size_t)b * 2048 * 6144 + 4096 + h * 128;
    const int t = threadIdx.x;
    const int c8 = (t & 7) * 8, r0 = t >> 3; // r0: 0..31
#pragma unroll
    for (int p = 0; p < 2; ++p) {
        int r = r0 + p * 32;
        const unsigned short* sp = &src[(size_t)(ts + r) * 6144 + td + c8];
        ushort4 a0 = *reinterpret_cast<const ushort4*>(sp);
        ushort4 a1 = *reinterpret_cast<const ushort4*>(sp + 4);
        tile[r][c8 + 0] = a0.x; tile[r][c8 + 1] = a0.y; tile[r][c8 + 2] = a0.z; tile[r][c8 + 3] = a0.w;
        tile[r][c8 + 4] = a1.x; tile[r][c8 + 5] = a1.y; tile[r][c8 + 6] = a1.z; tile[r][c8 + 7] = a1.w;
    }
    __syncthreads();
    unsigned short* dst = vt + ((size_t)bh * 128 + td) * 2048 + ts;
#pragma unroll
    for (int p = 0; p < 2; ++p) {
        int d = r0 + p * 32;
        ushort4 o0, o1;
        o0.x = tile[c8 + 0][d]; o0.y = tile[c8 + 1][d]; o0.z = tile[c8 + 2][d]; o0.w = tile[c8 + 3][d];
        o1.x = tile[c8 + 4][d]; o1.y = tile[c8 + 5][d]; o1.z = tile[c8 + 6][d]; o1.w = tile[c8 + 7][d];
        *reinterpret_cast<ushort4*>(&dst[(size_t)d * 2048 + c8]) = o0;
        *reinterpret_cast<ushort4*>(&dst[(size_t)d * 2048 + c8 + 4]) = o1;
    }
}

// ---------------- layernorm: fp32 [rows][2048] -> bf16, one block per row ----------------
__global__ __launch_bounds__(256) void k_layernorm(const float* __restrict__ x,
                                                   const float* __restrict__ g,
                                                   const float* __restrict__ bb,
                                                   unsigned short* __restrict__ out) {
    const int row = blockIdx.x;
    const int t = threadIdx.x;
    const float* xr = x + (size_t)row * 2048 + t * 8;
    float4 v0 = *reinterpret_cast<const float4*>(xr);
    float4 v1 = *reinterpret_cast<const float4*>(xr + 4);
    float s = (v0.x + v0.y) + (v0.z + v0.w) + (v1.x + v1.y) + (v1.z + v1.w);
    float ss = (v0.x * v0.x + v0.y * v0.y) + (v0.z * v0.z + v0.w * v0.w)
             + (v1.x * v1.x + v1.y * v1.y) + (v1.z * v1.z + v1.w * v1.w);
#pragma unroll
    for (int m = 1; m < 64; m <<= 1) { s += __shfl_xor(s, m); ss += __shfl_xor(ss, m); }
    __shared__ float red[8];
    if ((t & 63) == 0) { red[t >> 6] = s; red[4 + (t >> 6)] = ss; }
    __syncthreads();
    s = (red[0] + red[1]) + (red[2] + red[3]);
    ss = (red[4] + red[5]) + (red[6] + red[7]);
    const float mu = s * (1.f / 2048.f);
    const float rstd = rsqrtf(ss * (1.f / 2048.f) - mu * mu + 1e-5f);
    const float4 g0 = *reinterpret_cast<const float4*>(g + t * 8);
    const float4 g1 = *reinterpret_cast<const float4*>(g + t * 8 + 4);
    const float4 b0 = *reinterpret_cast<const float4*>(bb + t * 8);
    const float4 b1 = *reinterpret_cast<const float4*>(bb + t * 8 + 4);
    ushort8 o;
    o[0] = f2bf((v0.x - mu) * rstd * g0.x + b0.x);
    o[1] = f2bf((v0.y - mu) * rstd * g0.y + b0.y);
    o[2] = f2bf((v0.z - mu) * rstd * g0.z + b0.z);
    o[3] = f2bf((v0.w - mu) * rstd * g0.w + b0.w);
    o[4] = f2bf((v1.x - mu) * rstd * g1.x + b1.x);
    o[5] = f2bf((v1.y - mu) * rstd * g1.y + b1.y);
    o[6] = f2bf((v1.z - mu) * rstd * g1.z + b1.z);
    o[7] = f2bf((v1.w - mu) * rstd * g1.w + b1.w);
    *reinterpret_cast<ushort8*>(out + (size_t)row * 2048 + t * 8) = o;
}

// ---------------- GEMM: A[M][K]bf16 * Bt[N][K]bf16 + bias, epilogue variants ----------------
template <int EPI>
__global__ __launch_bounds__(256) void k_gemm_bt(const unsigned short* __restrict__ A,
                                                 const unsigned short* __restrict__ Bt,
                                                 const float* __restrict__ bias,
                                                 const float* __restrict__ res,
                                                 void* __restrict__ outv,
                                                 int M, int N, int K,
                                                 int scale_cols, float scale) {
    __shared__ alignas(16) unsigned short A_s[128 * 64];
    __shared__ alignas(16) unsigned short B_s[128 * 64];
    const int bn = blockIdx.x * 128, bm = blockIdx.y * 128;
    const int t = threadIdx.x, lane = t & 63, wid = t >> 6;
    const int wr = wid >> 1, wc = wid & 1;

    const unsigned short* agbase = A  + (size_t)(bm + wid * 32 + (lane >> 3)) * K + (lane & 7) * 8;
    const unsigned short* bgbase = Bt + (size_t)(bn + wid * 32 + (lane >> 3)) * K + (lane & 7) * 8;

    f32x4 acc[4][4] = {};
    for (int k0 = 0; k0 < K; k0 += 64) {
#pragma unroll
        for (int i = 0; i < 4; ++i) {
            load_lds_16(agbase + (size_t)i * 8 * K + k0, &A_s[(wid * 4 + i) * 512]);
            load_lds_16(bgbase + (size_t)i * 8 * K + k0, &B_s[(wid * 4 + i) * 512]);
        }
        __syncthreads();
#pragma unroll
        for (int kk = 0; kk < 64; kk += 32) {
            bf16x8 af[4], bf[4];
#pragma unroll
            for (int r = 0; r < 4; ++r)
                af[r] = *reinterpret_cast<const bf16x8*>(
                    &A_s[(wr * 64 + r * 16 + (lane & 15)) * 64 + kk + (lane >> 4) * 8]);
#pragma unroll
            for (int c = 0; c < 4; ++c)
                bf[c] = *reinterpret_cast<const bf16x8*>(
                    &B_s[(wc * 64 + c * 16 + (lane & 15)) * 64 + kk + (lane >> 4) * 8]);
#pragma unroll
            for (int r = 0; r < 4; ++r)
#pragma unroll
                for (int c = 0; c < 4; ++c)
                    acc[r][c] = __builtin_amdgcn_mfma_f32_16x16x32_bf16(af[r], bf[c], acc[r][c], 0, 0, 0);
        }
        __syncthreads();
    }

    const int row0 = bm + wr * 64 + ((lane >> 4) << 2);
    const int col0 = bn + wc * 64 + (lane & 15);
#pragma unroll
    for (int c = 0; c < 4; ++c) {
        const int col = col0 + c * 16;
        const float bv = bias[col];
        const float qs = (EPI == 0 && col < scale_cols) ? scale : 1.f;
#pragma unroll
        for (int r = 0; r < 4; ++r) {
            const int row = row0 + r * 16;
#pragma unroll
            for (int j = 0; j < 4; ++j) {
                float v = acc[r][c][j] + bv;
                const size_t idx = (size_t)(row + j) * N + col;
                if (EPI == 0) {
                    ((unsigned short*)outv)[idx] = f2bf(v * qs);
                } else if (EPI == 1) {
                    ((float*)outv)[idx] = v + res[idx];
                } else {
                    float u = v + 0.044715f * v * v * v;
                    u = fminf(fmaxf(u, -40.f), 40.f);
                    float e = __expf(1.5957691216057308f * u); // 2*sqrt(2/pi)
                    float th = (e - 1.f) / (e + 1.f);
                    ((unsigned short*)outv)[idx] = f2bf(0.5f * v * (1.f + th));
                }
            }
        }
    }
}

// ---------------- flash attention v2: LDS-staged K/V, dbuf, pair-balanced, causal ----------------
// grid = 1024: xcd = blk&7, idx = blk>>3, bh = xcd*8 + idx/16, pair = idx%16.
// Block handles q-tiles {31-pair, pair} (64 rows each) => uniform 33 k-tile iters.
__global__ __launch_bounds__(256) void k_attn(const unsigned short* __restrict__ qkv,
                                              const unsigned short* __restrict__ vt,
                                              unsigned short* __restrict__ out) {
    __shared__ alignas(16) unsigned short Ks[2][64 * 128];   // [s][d], granule-swizzled
    __shared__ alignas(16) unsigned short Vs[2][128 * 64];   // [d][s], granule-swizzled
    __shared__ alignas(16) unsigned short P_lds[4][16][72];

    const int p = blockIdx.x;
    const int bh = (p & 7) * 8 + ((p >> 3) >> 4);
    const int pair = (p >> 3) & 15;
    const int b = bh >> 4, h = bh & 15;
    const int t = threadIdx.x, lane = t & 63, wid = t >> 6;
    const int l15 = lane & 15, l4 = lane >> 4;

    // staging geometry (per wave: 4 K-chunks + 4 V-chunks of 1KB)
    const int kq = wid * 4;                 // first chunk index of this wave
    const int k_r0 = kq * 4 + (lane >> 4);  // K row for chunk kq (+i*4)
    const int k_g0 = lane & 15;             // physical granule (16B) within K row
    const int v_d0 = kq * 8 + (lane >> 3);  // V row (d) for chunk kq (+i*8)
    const int v_g0 = lane & 7;              // physical granule within V row

#pragma unroll
    for (int qi = 0; qi < 2; ++qi) {
        const int qt = qi ? pair : (31 - pair);
        const int qrow0 = qt * 64 + wid * 16;
        const int nt = qt + 1;

        // Q fragments (A-operand): row l15, k = l4*8 + s*32
        const unsigned short* qp = qkv + (size_t)(b * 2048 + qrow0 + l15) * 6144 + h * 128 + l4 * 8;
        bf16x8 aQ[4];
#pragma unroll
        for (int s = 0; s < 4; ++s) aQ[s] = *reinterpret_cast<const bf16x8*>(qp + s * 32);

        f32x4 oacc[8] = {};
        float m_run[4], l_run[4];
#pragma unroll
        for (int j = 0; j < 4; ++j) { m_run[j] = -1e30f; l_run[j] = 0.f; }

        // prologue: stage tile 0 into buffer 0
        {
#pragma unroll
            for (int i = 0; i < 4; ++i) {
                const int r = k_r0 + i * 4;
                const unsigned short* src = qkv + (size_t)(b * 2048 + r) * 6144 + 2048
                                            + h * 128 + (size_t)(k_g0 ^ (r & 7)) * 8;
                load_lds_16(src, &Ks[0][(kq + i) * 512]);
            }
#pragma unroll
            for (int i = 0; i < 4; ++i) {
                const int d = v_d0 + i * 8;
                const unsigned short* src = vt + ((size_t)bh * 128 + d) * 2048
                                            + (size_t)(v_g0 ^ (d & 7)) * 8;
                load_lds_16(src, &Vs[0][(kq + i) * 512]);
            }
        }

        for (int ti = 0; ti < nt; ++ti) {
            const int cur = ti & 1;
            const int k0 = ti * 64;
            if (ti + 1 < nt) {
                const int kn = k0 + 64;
#pragma unroll
                for (int i = 0; i < 4; ++i) {
                    const int r = k_r0 + i * 4;
                    const unsigned short* src = qkv + (size_t)(b * 2048 + kn + r) * 6144 + 2048
                                                + h * 128 + (size_t)(k_g0 ^ (r & 7)) * 8;
                    load_lds_16(src, &Ks[cur ^ 1][(kq + i) * 512]);
                }
#pragma unroll
                for (int i = 0; i < 4; ++i) {
                    const int d = v_d0 + i * 8;
                    const unsigned short* src = vt + ((size_t)bh * 128 + d) * 2048 + kn
                                                + (size_t)(v_g0 ^ (d & 7)) * 8;
                    load_lds_16(src, &Vs[cur ^ 1][(kq + i) * 512]);
                }
                asm volatile("s_waitcnt vmcnt(8)\n\ts_barrier" ::: "memory");
            } else {
                asm volatile("s_waitcnt vmcnt(0)\n\ts_barrier" ::: "memory");
            }

            // ---- QK^T from LDS ----
            f32x4 sc[4] = {};
#pragma unroll
            for (int s = 0; s < 4; ++s)
#pragma unroll
                for (int ct = 0; ct < 4; ++ct) {
                    bf16x8 bK = *reinterpret_cast<const bf16x8*>(
                        &Ks[cur][(ct * 16 + l15) * 128 + (((s * 4 + l4) ^ (l15 & 7)) << 3)]);
                    sc[ct] = __builtin_amdgcn_mfma_f32_16x16x32_bf16(aQ[s], bK, sc[ct], 0, 0, 0);
                }

            if (k0 + 63 > qrow0) { // causal mask for diagonal-crossing tiles
#pragma unroll
                for (int ct = 0; ct < 4; ++ct) {
                    int colc = k0 + ct * 16 + l15;
#pragma unroll
                    for (int j = 0; j < 4; ++j)
                        if (colc > qrow0 + l4 * 4 + j) sc[ct][j] = -1e30f;
                }
            }
            // ---- online softmax ----
            float alpha[4], tsum[4];
#pragma unroll
            for (int j = 0; j < 4; ++j) {
                float mx = fmaxf(fmaxf(sc[0][j], sc[1][j]), fmaxf(sc[2][j], sc[3][j]));
#pragma unroll
                for (int msk = 1; msk < 16; msk <<= 1) mx = fmaxf(mx, __shfl_xor(mx, msk));
                float mn = fmaxf(m_run[j], mx);
                alpha[j] = __expf(m_run[j] - mn);
                m_run[j] = mn;
                tsum[j] = 0.f;
            }
#pragma unroll
            for (int ct = 0; ct < 4; ++ct)
#pragma unroll
                for (int j = 0; j < 4; ++j) {
                    float pp = __expf(sc[ct][j] - m_run[j]);
                    sc[ct][j] = pp;
                    tsum[j] += pp;
                }
#pragma unroll
            for (int j = 0; j < 4; ++j) {
                float sm = tsum[j];
#pragma unroll
                for (int msk = 1; msk < 16; msk <<= 1) sm += __shfl_xor(sm, msk);
                l_run[j] = l_run[j] * alpha[j] + sm;
            }
#pragma unroll
            for (int dt = 0; dt < 8; ++dt)
#pragma unroll
                for (int j = 0; j < 4; ++j) oacc[dt][j] *= alpha[j];

            // ---- P (C-layout) -> per-wave LDS -> A-fragments ----
#pragma unroll
            for (int ct = 0; ct < 4; ++ct)
#pragma unroll
                for (int j = 0; j < 4; ++j)
                    P_lds[wid][l4 * 4 + j][ct * 16 + l15] = f2bf(sc[ct][j]);
            asm volatile("s_waitcnt lgkmcnt(0)" ::: "memory");
            // ---- PV from LDS ----
#pragma unroll
            for (int kk = 0; kk < 2; ++kk) {
                bf16x8 aP = *reinterpret_cast<const bf16x8*>(&P_lds[wid][l15][kk * 32 + l4 * 8]);
#pragma unroll
                for (int dt = 0; dt < 8; ++dt) {
                    bf16x8 bV = *reinterpret_cast<const bf16x8*>(
                        &Vs[cur][(dt * 16 + l15) * 64 + (((kk * 4 + l4) ^ (l15 & 7)) << 3)]);
                    oacc[dt] = __builtin_amdgcn_mfma_f32_16x16x32_bf16(aP, bV, oacc[dt], 0, 0, 0);
                }
            }
            asm volatile("s_waitcnt lgkmcnt(0)\n\ts_barrier" ::: "memory");
        }

        float inv_l[4];
#pragma unroll
        for (int j = 0; j < 4; ++j) inv_l[j] = 1.f / l_run[j];
        unsigned short* op = out + (size_t)(b * 2048 + qrow0 + l4 * 4) * 2048 + h * 128 + l15;
#pragma unroll
        for (int dt = 0; dt < 8; ++dt)
#pragma unroll
            for (int j = 0; j < 4; ++j)
                op[(size_t)j * 2048 + dt * 16] = f2bf(oacc[dt][j] * inv_l[j]);
    }
}

// ---------------- launch ----------------
extern "C" void kernel_launch(void* const* d_in, const int* in_sizes, int n_in,
                              void* d_out, int out_size, void* d_ws, size_t ws_size,
                              hipStream_t stream) {
    const float* hidden = (const float*)d_in[0];
    const float* ln1_g = (const float*)d_in[1];
    const float* ln1_b = (const float*)d_in[2];
    const float* w_attn = (const float*)d_in[3];
    const float* b_attn = (const float*)d_in[4];
    const float* w_o = (const float*)d_in[5];
    const float* b_o = (const float*)d_in[6];
    const float* ln2_g = (const float*)d_in[7];
    const float* ln2_b = (const float*)d_in[8];
    const float* w_fc = (const float*)d_in[9];
    const float* b_fc = (const float*)d_in[10];
    const float* w_fcp = (const float*)d_in[11];
    const float* b_fcp = (const float*)d_in[12];
    float* outp = (float*)d_out;

    if (ws_size < 268435456u) return; // need 256 MiB scratch

    char* ws = (char*)d_ws;
    unsigned short* wT_attn = (unsigned short*)(ws + 0);          // [6144][2048]
    unsigned short* wT_o    = (unsigned short*)(ws + 25165824);   // [2048][2048]
    unsigned short* wT_fc   = (unsigned short*)(ws + 33554432);   // [8192][2048]
    unsigned short* wT_proj = (unsigned short*)(ws + 67108864);   // [2048][8192]
    unsigned short* buf_x   = (unsigned short*)(ws + 100663296);  // [8192][2048] (x1 / attn / x2)
    unsigned short* qkv_b   = (unsigned short*)(ws + 134217728);  // [8192][6144]
    unsigned short* vtb     = (unsigned short*)(ws + 234881024);  // [64*128][2048]
    unsigned short* act_b   = qkv_b;                              // [8192][8192] overlays qkv+vt

    // 1. weight convert+transpose to bf16 [N][K]
    k_transpose_w<<<dim3(32, 96), 256, 0, stream>>>(w_attn, wT_attn, 2048, 6144);
    k_transpose_w<<<dim3(32, 32), 256, 0, stream>>>(w_o, wT_o, 2048, 2048);
    k_transpose_w<<<dim3(32, 128), 256, 0, stream>>>(w_fc, wT_fc, 2048, 8192);
    k_transpose_w<<<dim3(128, 32), 256, 0, stream>>>(w_fcp, wT_proj, 8192, 2048);
    // 2. LN1: hidden -> bf16 x
    k_layernorm<<<8192, 256, 0, stream>>>(hidden, ln1_g, ln1_b, buf_x);
    // 3. qkv = x @ w_attn + b_attn (Q cols pre-scaled by Dh^-0.5)
    k_gemm_bt<0><<<dim3(48, 64), 256, 0, stream>>>(buf_x, wT_attn, b_attn, (const float*)nullptr,
                                                   (void*)qkv_b, 8192, 6144, 2048,
                                                   2048, 0.08838834764831845f);
    // 4. V -> Vt [bh][d][s]
    k_transpose_v<<<dim3(32, 2, 64), 256, 0, stream>>>(qkv_b, vtb);
    // 5. causal flash attention -> buf_x (bf16)
    k_attn<<<1024, 256, 0, stream>>>(qkv_b, vtb, buf_x);
    // 6. hidden2 = attn @ w_o + b_o + hidden -> d_out (f32)
    k_gemm_bt<1><<<dim3(16, 64), 256, 0, stream>>>(buf_x, wT_o, b_o, hidden,
                                                   d_out, 8192, 2048, 2048, 0, 1.f);
    // 7. LN2: d_out -> bf16 x2
    k_layernorm<<<8192, 256, 0, stream>>>(outp, ln2_g, ln2_b, buf_x);
    // 8. act = gelu(x2 @ w_fc + b_fc) -> bf16
    k_gemm_bt<2><<<dim3(64, 64), 256, 0, stream>>>(buf_x, wT_fc, b_fc, (const float*)nullptr,
                                                   (void*)act_b, 8192, 8192, 2048, 0, 1.f);
    // 9. out = act @ w_fc_proj + b_fc_proj + hidden2 (in-place on d_out)
    k_gemm_bt<1><<<dim3(16, 64), 256, 0, stream>>>(act_b, wT_proj, b_fcp, outp,
                                                   d_out, 8192, 2048, 8192, 0, 1.f);
}